// Round 1
// baseline (899.723 us; speedup 1.0000x reference)
//
#include <hip/hip_runtime.h>

// Problem constants: B=32, S=4096, D=1024, fp32, mask int32.
#define BATCH  32
#define SEQ    4096
#define DIM    1024
#define NEGV   (-1e37f)
#define NCHUNK 64                 // S-chunks per batch -> grid (B, NCHUNK) = 2048 blocks
#define CHUNK  (SEQ / NCHUNK)     // 64 rows per block
#define RPW    (CHUNK / 4)        // 16 rows per wave (4 waves/block)

// ---------------- Kernel 1: fused flash-decode partial ----------------
// grid (BATCH, NCHUNK), block 256 (4 waves).
// Per block: masked QK logits for 64 rows -> chunk-local softmax (online style)
// -> weighted V accumulation -> write (partial_out[D], m, l).
__global__ __launch_bounds__(256) void attn_partial(
    const float* __restrict__ K, const float* __restrict__ Q,
    const float* __restrict__ V, const int* __restrict__ mask,
    float* __restrict__ part, float* __restrict__ ml) {
  const int b    = blockIdx.x;
  const int c    = blockIdx.y;
  const int s0   = c * CHUNK;
  const int tid  = threadIdx.x;
  const int lane = tid & 63;
  const int wave = tid >> 6;   // 0..3

  __shared__ float slog[CHUNK];

  // One vector mask load per wave covers all 64 chunk rows: bit li of bm =
  // mask valid for row s0+li. Removes the per-row load->branch dependency.
  const int mv = mask[(size_t)b * SEQ + s0 + lane];
  const unsigned long long bm = __ballot(mv != 0);

  // q fragment: lane holds d = {lane*4, 256+lane*4, 512+lane*4, 768+lane*4}
  const float4* q4 = (const float4*)(Q + (size_t)b * DIM);
  const float4 q0 = q4[lane];
  const float4 q1 = q4[64 + lane];
  const float4 q2 = q4[128 + lane];
  const float4 q3 = q4[192 + lane];

  // Phase A: logits. Wave w handles rows w*16 .. w*16+15.
  for (int r = 0; r < RPW; ++r) {
    const int li = wave * RPW + r;
    if (!((bm >> li) & 1ull)) {
      if (lane == 0) slog[li] = NEGV;
      continue;
    }
    const float4* k4 = (const float4*)(K + ((size_t)b * SEQ + s0 + li) * DIM);
    const float4 k0 = k4[lane];
    const float4 k1 = k4[64 + lane];
    const float4 k2 = k4[128 + lane];
    const float4 k3 = k4[192 + lane];
    float acc = q0.x*k0.x + q0.y*k0.y + q0.z*k0.z + q0.w*k0.w;
    acc      += q1.x*k1.x + q1.y*k1.y + q1.z*k1.z + q1.w*k1.w;
    acc      += q2.x*k2.x + q2.y*k2.y + q2.z*k2.z + q2.w*k2.w;
    acc      += q3.x*k3.x + q3.y*k3.y + q3.z*k3.z + q3.w*k3.w;
    for (int off = 32; off > 0; off >>= 1)
      acc += __shfl_down(acc, off, 64);
    if (lane == 0) slog[li] = acc;
  }
  __syncthreads();

  // Phase B: chunk max (redundant per thread; LDS broadcast reads are free).
  float m = NEGV;
  #pragma unroll
  for (int i = 0; i < CHUNK; ++i) m = fmaxf(m, slog[i]);
  // All-masked chunk => m == NEGV, loop below skips everything, lsum = 0,
  // and the combine kernel scales this chunk by exp(NEGV - M) == 0.

  // Phase C: weighted V accumulation. Thread owns 4 contiguous d (float4).
  float4 acc = make_float4(0.f, 0.f, 0.f, 0.f);
  float lsum = 0.f;
  for (int i = 0; i < CHUNK; ++i) {
    const float l = slog[i];
    if (l == NEGV) continue;           // masked row: skip the 4 KB V read
    const float e = __expf(l - m);     // e in (0, 1]
    lsum += e;                         // same value in every thread
    const float4 v = ((const float4*)(V + ((size_t)b * SEQ + s0 + i) * DIM))[tid];
    acc.x += e * v.x; acc.y += e * v.y; acc.z += e * v.z; acc.w += e * v.w;
  }

  ((float4*)(part + ((size_t)b * NCHUNK + c) * DIM))[tid] = acc;
  if (tid == 0)
    ((float2*)ml)[(size_t)b * NCHUNK + c] = make_float2(m, lsum);
}

// ---------------- Kernel 2: combine partials with rescale ----------------
// grid BATCH, block 256. out[d] = sum_c exp(m_c - M) * part[c][d] / denom,
// denom = sum_c exp(m_c - M) * l_c.
__global__ __launch_bounds__(256) void attn_combine(
    const float* __restrict__ part, const float* __restrict__ ml,
    float* __restrict__ out) {
  const int b   = blockIdx.x;
  const int tid = threadIdx.x;
  __shared__ float sm[NCHUNK];
  __shared__ float sl[NCHUNK];
  if (tid < NCHUNK) {
    const float2 v = ((const float2*)ml)[(size_t)b * NCHUNK + tid];
    sm[tid] = v.x;
    sl[tid] = v.y;
  }
  __syncthreads();

  float M = -3.4e38f;
  #pragma unroll
  for (int i = 0; i < NCHUNK; ++i) M = fmaxf(M, sm[i]);

  float4 acc = make_float4(0.f, 0.f, 0.f, 0.f);
  float denom = 0.f;
  for (int cc = 0; cc < NCHUNK; ++cc) {
    const float sc = __expf(sm[cc] - M);   // 0 for all-masked chunks
    denom += sc * sl[cc];
    const float4 p = ((const float4*)(part + ((size_t)b * NCHUNK + cc) * DIM))[tid];
    acc.x += sc * p.x; acc.y += sc * p.y; acc.z += sc * p.z; acc.w += sc * p.w;
  }
  const float inv = 1.0f / denom;
  acc.x *= inv; acc.y *= inv; acc.z *= inv; acc.w *= inv;
  ((float4*)(out + (size_t)b * DIM))[tid] = acc;
}

extern "C" void kernel_launch(void* const* d_in, const int* in_sizes, int n_in,
                              void* d_out, int out_size, void* d_ws, size_t ws_size,
                              hipStream_t stream) {
  const float* keys    = (const float*)d_in[0];
  const float* queries = (const float*)d_in[1];
  const float* values  = (const float*)d_in[2];
  const int*   mask    = (const int*)d_in[3];
  float* out = (float*)d_out;

  // ws layout: [part: B*NCHUNK*D floats = 8 MiB][ml: B*NCHUNK float2 = 16 KiB]
  float* part = (float*)d_ws;
  float* ml   = part + (size_t)BATCH * NCHUNK * DIM;

  attn_partial<<<dim3(BATCH, NCHUNK), 256, 0, stream>>>(keys, queries, values, mask, part, ml);
  attn_combine<<<BATCH, 256, 0, stream>>>(part, ml, out);
}